// Round 1
// baseline (3781.161 us; speedup 1.0000x reference)
//
#include <hip/hip_runtime.h>
#include <math.h>

// ViT encoder block (DeepViT ReAttention), B=4 N=1024 D=768 H=8 hd=96 Hdim=3072
// All fp32 correctness-first baseline.
//
// ws layout (floats):
//  [0,64)        stats: [0..15] BN sum/sumsq per head, [16..23] LN1 per-b sum/sumsq, [24..31] LN2
//  [64, 65600)   pstat: 4096 blocks x 16 BN partials
//  qb (3145728), kb (3145728), vb (3145728), ub (3145728), vcs (3072), hb (12582912)
//  aliases: y1 = qb, x1 = kb, y2 = vb   (safe: q/k/v dead after attention pass)

#define EPSV 1e-5f

// ---------------------------------------------------------------- conv 3x3 QKV
__global__ __launch_bounds__(256) void k_conv(const float* __restrict__ x,
    const float* __restrict__ wq, const float* __restrict__ wk, const float* __restrict__ wv,
    float* __restrict__ qb, float* __restrict__ kb, float* __restrict__ vb)
{
  __shared__ float patch[768], swq[81], swk[81], swv[81];
  int bid = blockIdx.x;            // b*1024 + n
  int b = bid >> 10, n = bid & 1023;
  int t = threadIdx.x;
  const float* xr = x + (size_t)bid * 768;
  patch[t] = xr[t]; patch[t + 256] = xr[t + 256]; patch[t + 512] = xr[t + 512];
  if (t < 81) { swq[t] = wq[t]; swk[t] = wk[t]; swv[t] = wv[t]; }
  __syncthreads();
  #pragma unroll
  for (int r = 0; r < 3; ++r) {
    int f = t + 256 * r;                       // c*256 + p*16 + q flat conv-out index
    int o = f >> 8, rem = f & 255, pp = rem >> 4, qq = rem & 15;
    float aq = 0.f, ak = 0.f, av = 0.f;
    #pragma unroll
    for (int i = 0; i < 3; ++i)
      #pragma unroll
      for (int dp = 0; dp < 3; ++dp) {
        int ip = pp + dp - 1;
        if (ip < 0 || ip > 15) continue;
        #pragma unroll
        for (int dq = 0; dq < 3; ++dq) {
          int iq = qq + dq - 1;
          if (iq < 0 || iq > 15) continue;
          float pv = patch[i * 256 + ip * 16 + iq];
          int wi = ((o * 3 + i) * 3 + dp) * 3 + dq;
          aq += swq[wi] * pv; ak += swk[wi] * pv; av += swv[wi] * pv;
        }
      }
    int h = f / 96, d = f - h * 96;
    size_t oi = ((size_t)(b * 8 + h) * 1024 + n) * 96 + d;  // [B,H,N,hd]
    qb[oi] = aq; kb[oi] = ak; vb[oi] = av;
  }
}

// ------------------------------------------------- block reduce (sum or max)
__device__ __forceinline__ float bred(float v, float* red, bool domax) {
  int lane = threadIdx.x & 63, wid = threadIdx.x >> 6;
  #pragma unroll
  for (int off = 32; off > 0; off >>= 1) {
    float o = __shfl_down(v, off);
    v = domax ? fmaxf(v, o) : v + o;
  }
  if (lane == 0) red[wid] = v;
  __syncthreads();
  float r = domax ? fmaxf(fmaxf(red[0], red[1]), fmaxf(red[2], red[3]))
                  : (red[0] + red[1]) + (red[2] + red[3]);
  __syncthreads();
  return r;
}

// --------------- fused attention: scores(all heads) -> softmax -> head-mix ->
// --------------- BN stat partials -> U = attn2 @ V (un-normalized)
__global__ __launch_bounds__(256) void k_attn(const float* __restrict__ qb,
    const float* __restrict__ kb, const float* __restrict__ vb,
    const float* __restrict__ rw, const float* __restrict__ rbias,
    float* __restrict__ ub, float* __restrict__ pstat)
{
  __shared__ float qrow[768];
  __shared__ float S[8 * 1024];
  __shared__ float red[4];
  __shared__ float wl[64], cl[8];
  int bid = blockIdx.x, b = bid >> 10, n = bid & 1023;
  int t = threadIdx.x;
  #pragma unroll
  for (int r = 0; r < 3; ++r) {
    int f = t + 256 * r;
    int h = f / 96, d = f - h * 96;
    qrow[f] = qb[((size_t)(b * 8 + h) * 1024 + n) * 96 + d];   // qrow[h*96+d]
  }
  if (t < 64) wl[t] = rw[t];
  if (t < 8) cl[t] = rbias[t];
  __syncthreads();

  const float scale = 0.10206207261596575f;  // 96^-0.5
  // scores S[h][m]
  for (int h = 0; h < 8; ++h) {
    const float4* q4 = (const float4*)&qrow[h * 96];
    for (int m = t; m < 1024; m += 256) {
      const float4* k4 = (const float4*)(kb + ((size_t)(b * 8 + h) * 1024 + m) * 96);
      float acc = 0.f;
      #pragma unroll
      for (int u = 0; u < 24; ++u) {
        float4 a = q4[u], c = k4[u];
        acc += a.x * c.x + a.y * c.y + a.z * c.z + a.w * c.w;
      }
      S[h * 1024 + m] = acc * scale;
    }
  }
  __syncthreads();

  // softmax per head (each thread owns columns m = t + 256*j)
  for (int h = 0; h < 8; ++h) {
    float lm = -1e30f;
    #pragma unroll
    for (int j = 0; j < 4; ++j) lm = fmaxf(lm, S[h * 1024 + t + 256 * j]);
    float M = bred(lm, red, true);
    float ls = 0.f;
    #pragma unroll
    for (int j = 0; j < 4; ++j) {
      float e = __expf(S[h * 1024 + t + 256 * j] - M);
      S[h * 1024 + t + 256 * j] = e;
      ls += e;
    }
    float Z = bred(ls, red, false);
    float inv = 1.f / Z;
    #pragma unroll
    for (int j = 0; j < 4; ++j) S[h * 1024 + t + 256 * j] *= inv;
  }

  // head mix (in place, column-exclusive) + local BN stats
  float lsum[8] = {0,0,0,0,0,0,0,0}, lssq[8] = {0,0,0,0,0,0,0,0};
  #pragma unroll
  for (int j = 0; j < 4; ++j) {
    int m = t + 256 * j;
    float a[8];
    #pragma unroll
    for (int h = 0; h < 8; ++h) a[h] = S[h * 1024 + m];
    #pragma unroll
    for (int g = 0; g < 8; ++g) {
      float v = cl[g];
      #pragma unroll
      for (int h = 0; h < 8; ++h) v += wl[g * 8 + h] * a[h];
      S[g * 1024 + m] = v;
      lsum[g] += v; lssq[g] += v * v;
    }
  }
  __syncthreads();

  // BN stat partials (deterministic; reduced by k_vcs)
  for (int g = 0; g < 8; ++g) {
    float s = bred(lsum[g], red, false);
    float ss = bred(lssq[g], red, false);
    if (t == 0) { pstat[(size_t)bid * 16 + g] = s; pstat[(size_t)bid * 16 + 8 + g] = ss; }
  }

  // U[g][d] = sum_m attn2[g][m] * v[b,g,m,d]
  #pragma unroll
  for (int r = 0; r < 3; ++r) {
    int f = t + 256 * r;
    int g = f / 96, d = f - g * 96;
    const float* vp = vb + ((size_t)(b * 8 + g) * 1024) * 96 + d;
    float acc = 0.f;
    #pragma unroll 4
    for (int m = 0; m < 1024; ++m)
      acc = fmaf(S[g * 1024 + m], vp[(size_t)m * 96], acc);
    ub[(size_t)bid * 768 + f] = acc;   // [B,N, g*96+d]  (already transposed layout)
  }
}

// ------------------- vcolsum (blocks 0..31) + BN partial reduce (blocks 32..47)
__global__ __launch_bounds__(256) void k_vcs(const float* __restrict__ vb,
    const float* __restrict__ pstat, float* __restrict__ vcs, float* __restrict__ stats)
{
  __shared__ float red[4];
  int bid = blockIdx.x, t = threadIdx.x;
  if (bid < 32) {
    if (t < 96) {
      const float* vp = vb + (size_t)bid * 1024 * 96 + t;
      float acc = 0.f;
      for (int m = 0; m < 1024; ++m) acc += vp[(size_t)m * 96];
      vcs[bid * 96 + t] = acc;
    }
  } else {
    int j = bid - 32;   // 0..15
    float acc = 0.f;
    for (int i = t; i < 4096; i += 256) acc += pstat[(size_t)i * 16 + j];
    #pragma unroll
    for (int off = 32; off > 0; off >>= 1) acc += __shfl_down(acc, off);
    int lane = t & 63, wid = t >> 6;
    if (lane == 0) red[wid] = acc;
    __syncthreads();
    if (t == 0) stats[j] = red[0] + red[1] + red[2] + red[3];
  }
}

// ---------------------------- apply BN affine: AO = sg*U + tg*colsum(V) (in place)
__global__ __launch_bounds__(256) void k_bnfin(float* __restrict__ ub,
    const float* __restrict__ vcs, const float* __restrict__ stats,
    const float* __restrict__ bng, const float* __restrict__ bnb)
{
  size_t idx = (size_t)blockIdx.x * 256 + threadIdx.x;   // < 3145728
  int col = (int)(idx % 768); int i = (int)(idx / 768); int b = i >> 10;
  int g = col / 96, d = col - g * 96;
  const float cnt = 4194304.f;  // B*N*N
  float mu = stats[g] / cnt;
  float var = stats[8 + g] / cnt - mu * mu;
  float sg = bng[g] * rsqrtf(var + EPSV);
  float tg = bnb[g] - mu * sg;
  ub[idx] = sg * ub[idx] + tg * vcs[(b * 8 + g) * 96 + d];
}

__device__ __forceinline__ float gelu_exact(float v) {
  return 0.5f * v * (1.f + erff(v * 0.70710678118654752f));
}

// ------------------------- GEMM: out = A[M,K] @ W[N,K]^T + bias (+res)(+gelu)(+LN stats)
template<bool GELU_, bool RES_, bool STATS_>
__global__ __launch_bounds__(256) void k_gemm(const float* __restrict__ A,
    const float* __restrict__ W, const float* __restrict__ bias,
    const float* __restrict__ res, float* __restrict__ out,
    int K, int Nc, float* __restrict__ stats)
{
  __shared__ float As[16 * 64], Bs[16 * 64];
  int j0 = blockIdx.x * 64, i0 = blockIdx.y * 64;
  int t = threadIdx.x, tx = t & 15, ty = t >> 4;
  int lrow = t >> 2, lq = t & 3;
  float acc[4][4] = {};
  const float* Ap = A + (size_t)(i0 + lrow) * K + lq * 4;
  const float* Wp = W + (size_t)(j0 + lrow) * K + lq * 4;
  for (int k0 = 0; k0 < K; k0 += 16) {
    float4 av = *(const float4*)(Ap + k0);
    float4 wv = *(const float4*)(Wp + k0);
    As[(lq * 4 + 0) * 64 + lrow] = av.x;
    As[(lq * 4 + 1) * 64 + lrow] = av.y;
    As[(lq * 4 + 2) * 64 + lrow] = av.z;
    As[(lq * 4 + 3) * 64 + lrow] = av.w;
    Bs[(lq * 4 + 0) * 64 + lrow] = wv.x;
    Bs[(lq * 4 + 1) * 64 + lrow] = wv.y;
    Bs[(lq * 4 + 2) * 64 + lrow] = wv.z;
    Bs[(lq * 4 + 3) * 64 + lrow] = wv.w;
    __syncthreads();
    #pragma unroll
    for (int kk = 0; kk < 16; ++kk) {
      float4 a = *(const float4*)&As[kk * 64 + ty * 4];
      float4 bb = *(const float4*)&Bs[kk * 64 + tx * 4];
      float avr[4] = {a.x, a.y, a.z, a.w}, bvr[4] = {bb.x, bb.y, bb.z, bb.w};
      #pragma unroll
      for (int u = 0; u < 4; ++u)
        #pragma unroll
        for (int v = 0; v < 4; ++v) acc[u][v] = fmaf(avr[u], bvr[v], acc[u][v]);
    }
    __syncthreads();
  }
  float ls = 0.f, lss = 0.f;
  #pragma unroll
  for (int u = 0; u < 4; ++u) {
    int i = i0 + ty * 4 + u;
    #pragma unroll
    for (int v = 0; v < 4; ++v) {
      int j = j0 + tx * 4 + v;
      float val = acc[u][v] + bias[j];
      if (RES_) val += res[(size_t)i * Nc + j];
      if (GELU_) val = gelu_exact(val);
      out[(size_t)i * Nc + j] = val;
      if (STATS_) { ls += val; lss += val * val; }
    }
  }
  if (STATS_) {
    #pragma unroll
    for (int off = 32; off > 0; off >>= 1) { ls += __shfl_down(ls, off); lss += __shfl_down(lss, off); }
    int lane = t & 63, wid = t >> 6;
    if (lane == 0) { As[wid] = ls; Bs[wid] = lss; }
    __syncthreads();
    if (t == 0) {
      int b = i0 >> 10;
      atomicAdd(&stats[b * 2],     As[0] + As[1] + As[2] + As[3]);
      atomicAdd(&stats[b * 2 + 1], Bs[0] + Bs[1] + Bs[2] + Bs[3]);
    }
  }
}

// ------------------------------------ joint (N,D) LayerNorm apply (per-b scalar stats)
__global__ __launch_bounds__(256) void k_ln(const float* __restrict__ y,
    const float* __restrict__ stats, const float* __restrict__ g,
    const float* __restrict__ bta, float* __restrict__ outp)
{
  size_t idx = (size_t)blockIdx.x * 256 + threadIdx.x;
  int i = (int)(idx / 768), col = (int)(idx % 768);
  int b = i >> 10, n = i & 1023;
  const float cnt = 786432.f;  // N*D
  float mu = stats[b * 2] / cnt;
  float var = stats[b * 2 + 1] / cnt - mu * mu;
  float r = rsqrtf(var + EPSV);
  size_t gi = (size_t)n * 768 + col;
  outp[idx] = (y[idx] - mu) * r * g[gi] + bta[gi];
}

extern "C" void kernel_launch(void* const* d_in, const int* in_sizes, int n_in,
                              void* d_out, int out_size, void* d_ws, size_t ws_size,
                              hipStream_t stream)
{
  const float* x   = (const float*)d_in[0];
  const float* qw  = (const float*)d_in[1];
  const float* kw  = (const float*)d_in[2];
  const float* vw  = (const float*)d_in[3];
  const float* rw  = (const float*)d_in[4];
  const float* rb  = (const float*)d_in[5];
  const float* bng = (const float*)d_in[6];
  const float* bnb = (const float*)d_in[7];
  const float* pw  = (const float*)d_in[8];
  const float* pb  = (const float*)d_in[9];
  const float* lng = (const float*)d_in[10];
  const float* lnb = (const float*)d_in[11];
  const float* fw1 = (const float*)d_in[12];
  const float* fb1 = (const float*)d_in[13];
  const float* fw2 = (const float*)d_in[14];
  const float* fb2 = (const float*)d_in[15];
  float* out = (float*)d_out;

  float* ws    = (float*)d_ws;
  float* stats = ws;                  // 64
  float* pstat = ws + 64;             // 65536
  float* qb    = ws + 65600;          // 3145728
  float* kb    = qb + 3145728;
  float* vb    = kb + 3145728;
  float* ub    = vb + 3145728;
  float* vcs   = ub + 3145728;        // 3072
  float* hb    = vcs + 3072;          // 12582912
  float* y1 = qb;  // aliases (q/k/v dead after attention+vcs)
  float* x1 = kb;
  float* y2 = vb;

  hipMemsetAsync(stats, 0, 64 * sizeof(float), stream);

  k_conv<<<4096, 256, 0, stream>>>(x, qw, kw, vw, qb, kb, vb);
  k_attn<<<4096, 256, 0, stream>>>(qb, kb, vb, rw, rb, ub, pstat);
  k_vcs<<<48, 256, 0, stream>>>(vb, pstat, vcs, stats);
  k_bnfin<<<12288, 256, 0, stream>>>(ub, vcs, stats, bng, bnb);

  dim3 g1(12, 64);
  k_gemm<false, true, true><<<g1, 256, 0, stream>>>(ub, pw, pb, x, y1, 768, 768, stats + 16);
  k_ln<<<12288, 256, 0, stream>>>(y1, stats + 16, lng, lnb, x1);

  dim3 g2(48, 64);
  k_gemm<true, false, false><<<g2, 256, 0, stream>>>(x1, fw1, fb1, nullptr, hb, 768, 3072, nullptr);
  dim3 g3(12, 64);
  k_gemm<false, true, true><<<g3, 256, 0, stream>>>(hb, fw2, fb2, x1, y2, 3072, 768, stats + 24);
  k_ln<<<12288, 256, 0, stream>>>(y2, stats + 24, lng, lnb, out);
}

// Round 2
// 396.801 us; speedup vs baseline: 9.5291x; 9.5291x over previous
//
#include <hip/hip_runtime.h>
#include <math.h>

// ViT encoder block (DeepViT ReAttention), B=4 N=1024 D=768 H=8 hd=96 Hdim=3072
// MFMA bf16 attention (split-bf16 scores, analytic centering) + MFMA bf16 GEMMs.

typedef unsigned short u16;
typedef unsigned int u32;
typedef __bf16 bf16x8 __attribute__((ext_vector_type(8)));
typedef float f32x4 __attribute__((ext_vector_type(4)));

#define EPSV 1e-5f
#define SCALE 0.10206207261596575f  // 96^-0.5

__device__ __forceinline__ u16 f2bf(float f) {
  union { float f; u32 u; } v; v.f = f;
  u32 u = v.u + 0x7fffu + ((v.u >> 16) & 1u);
  return (u16)(u >> 16);
}
__device__ __forceinline__ float bf2f(u16 h) {
  union { u32 u; float f; } v; v.u = ((u32)h) << 16; return v.f;
}
__device__ __forceinline__ f32x4 mfma16(bf16x8 a, bf16x8 b, f32x4 c) {
  return __builtin_amdgcn_mfma_f32_16x16x32_bf16(a, b, c, 0, 0, 0);
}
__device__ __forceinline__ void gload16(const void* gp, void* lp) {
  __builtin_amdgcn_global_load_lds(
      (const __attribute__((address_space(1))) u32*)gp,
      (__attribute__((address_space(3))) u32*)lp, 16, 0, 0);
}

// ---------------------------------------------------------------- fp32 -> bf16
__global__ __launch_bounds__(256) void k_f2b(const float* __restrict__ s,
                                             u16* __restrict__ d, int n) {
  int i = blockIdx.x * 256 + threadIdx.x;
  int stride = gridDim.x * 256;
  for (; i < n; i += stride) d[i] = f2bf(s[i]);
}

// ---------------------------------------------------------------- conv 3x3 QKV
__global__ __launch_bounds__(256) void k_conv(const float* __restrict__ x,
    const float* __restrict__ wq, const float* __restrict__ wk, const float* __restrict__ wv,
    u16* __restrict__ qhi, u16* __restrict__ qlo,
    u16* __restrict__ khi, u16* __restrict__ klo,
    float* __restrict__ vb, u16* __restrict__ vtr)
{
  __shared__ float patch[768], swq[81], swk[81], swv[81];
  int bid = blockIdx.x;            // b*1024 + n
  int b = bid >> 10, n = bid & 1023;
  int t = threadIdx.x;
  const float* xr = x + (size_t)bid * 768;
  patch[t] = xr[t]; patch[t + 256] = xr[t + 256]; patch[t + 512] = xr[t + 512];
  if (t < 81) { swq[t] = wq[t]; swk[t] = wk[t]; swv[t] = wv[t]; }
  __syncthreads();
  #pragma unroll
  for (int r = 0; r < 3; ++r) {
    int f = t + 256 * r;                       // c*256 + p*16 + q
    int o = f >> 8, rem = f & 255, pp = rem >> 4, qq = rem & 15;
    float aq = 0.f, ak = 0.f, av = 0.f;
    #pragma unroll
    for (int i = 0; i < 3; ++i)
      #pragma unroll
      for (int dp = 0; dp < 3; ++dp) {
        int ip = pp + dp - 1;
        if (ip < 0 || ip > 15) continue;
        #pragma unroll
        for (int dq = 0; dq < 3; ++dq) {
          int iq = qq + dq - 1;
          if (iq < 0 || iq > 15) continue;
          float pv = patch[i * 256 + ip * 16 + iq];
          int wi = ((o * 3 + i) * 3 + dp) * 3 + dq;
          aq += swq[wi] * pv; ak += swk[wi] * pv; av += swv[wi] * pv;
        }
      }
    int h = f / 96, d = f - h * 96;
    size_t oi = ((size_t)(b * 8 + h) * 1024 + n) * 96 + d;
    u16 qh_ = f2bf(aq); qhi[oi] = qh_; qlo[oi] = f2bf(aq - bf2f(qh_));
    u16 kh_ = f2bf(ak); khi[oi] = kh_; klo[oi] = f2bf(ak - bf2f(kh_));
    vb[oi] = av;
    vtr[((size_t)(b * 8 + h) * 96 + d) * 1024 + n] = f2bf(av);
  }
}

// ---------------- pass A: row max + exp-sum per (b,h,n) via split-bf16 MFMA QK^T
__global__ __launch_bounds__(256) void k_passA(
    const u16* __restrict__ qhi, const u16* __restrict__ qlo,
    const u16* __restrict__ khi, const u16* __restrict__ klo,
    float* __restrict__ mz)
{
  int bid = blockIdx.x;
  int bh = bid >> 4, tile = bid & 15;
  int t = threadIdx.x, lane = t & 63, wv = t >> 6;
  int l15 = lane & 15, lhi = lane >> 4;
  int n0 = tile * 64 + wv * 16;
  size_t qoff = ((size_t)bh * 1024 + n0 + l15) * 96 + lhi * 8;
  bf16x8 qh[3], ql[3];
  #pragma unroll
  for (int kk = 0; kk < 3; ++kk) {
    qh[kk] = *(const bf16x8*)(qhi + qoff + kk * 32);
    ql[kk] = *(const bf16x8*)(qlo + qoff + kk * 32);
  }
  float mx[4] = {-1e30f, -1e30f, -1e30f, -1e30f};
  float zs[4] = {0.f, 0.f, 0.f, 0.f};
  for (int m0 = 0; m0 < 1024; m0 += 32) {
    #pragma unroll
    for (int msub = 0; msub < 2; ++msub) {
      size_t koff = ((size_t)bh * 1024 + m0 + msub * 16 + l15) * 96 + lhi * 8;
      f32x4 C = {0.f, 0.f, 0.f, 0.f};
      #pragma unroll
      for (int kk = 0; kk < 3; ++kk) {
        bf16x8 kh = *(const bf16x8*)(khi + koff + kk * 32);
        bf16x8 kl = *(const bf16x8*)(klo + koff + kk * 32);
        C = mfma16(qh[kk], kh, C);
        C = mfma16(qh[kk], kl, C);
        C = mfma16(ql[kk], kh, C);
      }
      #pragma unroll
      for (int r = 0; r < 4; ++r) {
        float v = C[r] * SCALE;
        float nm = fmaxf(mx[r], v);
        zs[r] = zs[r] * __expf(mx[r] - nm) + __expf(v - nm);
        mx[r] = nm;
      }
    }
  }
  #pragma unroll
  for (int off = 1; off < 16; off <<= 1) {
    #pragma unroll
    for (int r = 0; r < 4; ++r) {
      float om = __shfl_xor(mx[r], off);
      float oz = __shfl_xor(zs[r], off);
      float nm = fmaxf(mx[r], om);
      zs[r] = zs[r] * __expf(mx[r] - nm) + oz * __expf(om - nm);
      mx[r] = nm;
    }
  }
  if (l15 == 0) {
    #pragma unroll
    for (int r = 0; r < 4; ++r) {
      int idx = bh * 1024 + n0 + lhi * 4 + r;
      mz[idx] = mx[r];
      mz[32768 + idx] = 1.f / zs[r];
    }
  }
}

// ---------------- pass B: P (softmax) -> centered head-mix -> BN stats + U = c@V
__global__ __launch_bounds__(512) void k_passB(
    const u16* __restrict__ qhi, const u16* __restrict__ qlo,
    const u16* __restrict__ khi, const u16* __restrict__ klo,
    const u16* __restrict__ vtr, const float* __restrict__ mz,
    const float* __restrict__ rw, float* __restrict__ U, float* __restrict__ pstat)
{
  __shared__ float P[8 * 512];        // [h][n(16)][m(32)] swizzled
  __shared__ float Msm[128], Zsm[128];
  int bid = blockIdx.x;
  int b = bid >> 6, tile = bid & 63;
  int n0 = tile * 16;
  int t = threadIdx.x, lane = t & 63, wv = t >> 6;  // wv = head
  int l15 = lane & 15, lhi = lane >> 4;
  if (t < 128) {
    int h = t >> 4, rr = t & 15;
    int idx = (b * 8 + h) * 1024 + n0 + rr;
    Msm[t] = mz[idx];
    Zsm[t] = mz[32768 + idx];
  }
  float wg[8]; float wsum = 0.f;
  #pragma unroll
  for (int h = 0; h < 8; ++h) { wg[h] = rw[wv * 8 + h]; wsum += wg[h]; }
  float cg = -wsum * (1.f / 1024.f);   // analytic centering (reatten_b cancels)
  size_t qoff = ((size_t)(b * 8 + wv) * 1024 + n0 + l15) * 96 + lhi * 8;
  bf16x8 qh[3], ql[3];
  #pragma unroll
  for (int kk = 0; kk < 3; ++kk) {
    qh[kk] = *(const bf16x8*)(qhi + qoff + kk * 32);
    ql[kk] = *(const bf16x8*)(qlo + qoff + kk * 32);
  }
  f32x4 acc[6];
  #pragma unroll
  for (int ds = 0; ds < 6; ++ds) acc[ds] = (f32x4){0.f, 0.f, 0.f, 0.f};
  float sc = 0.f, scc = 0.f;
  __syncthreads();
  for (int m0 = 0; m0 < 1024; m0 += 32) {
    #pragma unroll
    for (int msub = 0; msub < 2; ++msub) {
      size_t koff = ((size_t)(b * 8 + wv) * 1024 + m0 + msub * 16 + l15) * 96 + lhi * 8;
      f32x4 C = {0.f, 0.f, 0.f, 0.f};
      #pragma unroll
      for (int kk = 0; kk < 3; ++kk) {
        bf16x8 kh = *(const bf16x8*)(khi + koff + kk * 32);
        bf16x8 kl = *(const bf16x8*)(klo + koff + kk * 32);
        C = mfma16(qh[kk], kh, C);
        C = mfma16(qh[kk], kl, C);
        C = mfma16(ql[kk], kh, C);
      }
      #pragma unroll
      for (int r = 0; r < 4; ++r) {
        int n = lhi * 4 + r;
        float p = __expf(C[r] * SCALE - Msm[wv * 16 + n]) * Zsm[wv * 16 + n];
        int m = msub * 16 + l15;
        P[wv * 512 + n * 32 + (m ^ (4 * (n & 7)))] = p;
      }
    }
    __syncthreads();
    {
      int n = l15, mask = 4 * (n & 7);
      int m0r = lhi * 8;
      float c8[8];
      #pragma unroll
      for (int j = 0; j < 8; ++j) c8[j] = cg;
      #pragma unroll
      for (int h = 0; h < 8; ++h) {
        const float* Ph = &P[h * 512 + n * 32];
        float4 p0 = *(const float4*)&Ph[(m0r) ^ mask];
        float4 p1 = *(const float4*)&Ph[(m0r + 4) ^ mask];
        c8[0] += wg[h] * p0.x; c8[1] += wg[h] * p0.y;
        c8[2] += wg[h] * p0.z; c8[3] += wg[h] * p0.w;
        c8[4] += wg[h] * p1.x; c8[5] += wg[h] * p1.y;
        c8[6] += wg[h] * p1.z; c8[7] += wg[h] * p1.w;
      }
      union { u16 us[8]; bf16x8 bv; } pk;
      #pragma unroll
      for (int j = 0; j < 8; ++j) {
        sc += c8[j]; scc += c8[j] * c8[j];
        pk.us[j] = f2bf(c8[j]);
      }
      #pragma unroll
      for (int ds = 0; ds < 6; ++ds) {
        size_t voff = ((size_t)(b * 8 + wv) * 96 + ds * 16 + l15) * 1024 + m0 + lhi * 8;
        bf16x8 bv = *(const bf16x8*)(vtr + voff);
        acc[ds] = mfma16(pk.bv, bv, acc[ds]);
      }
    }
    __syncthreads();
  }
  #pragma unroll
  for (int ds = 0; ds < 6; ++ds)
    #pragma unroll
    for (int r = 0; r < 4; ++r) {
      int n = lhi * 4 + r;
      U[((size_t)(b * 1024 + n0 + n)) * 768 + wv * 96 + ds * 16 + l15] = acc[ds][r];
    }
  #pragma unroll
  for (int off = 32; off > 0; off >>= 1) {
    sc += __shfl_down(sc, off); scc += __shfl_down(scc, off);
  }
  if (lane == 0) { pstat[bid * 16 + wv] = sc; pstat[bid * 16 + 8 + wv] = scc; }
}

// ------------------------------------------------- colsum(V) per (b,h,d), fp32
__global__ __launch_bounds__(384) void k_vcs(const float* __restrict__ vb,
                                             float* __restrict__ vcs)
{
  __shared__ float part[4][96];
  int bh = blockIdx.x, t = threadIdx.x;
  int c = t % 96, g4 = t / 96;
  float a = 0.f;
  const float* vp = vb + (size_t)bh * 98304 + (size_t)g4 * 24576 + c;
  for (int m = 0; m < 256; ++m) a += vp[m * 96];
  part[g4][c] = a;
  __syncthreads();
  if (t < 96) vcs[bh * 96 + t] = part[0][t] + part[1][t] + part[2][t] + part[3][t];
}

// ------------------------------------------------- BN partial reduce (256x16)
__global__ __launch_bounds__(256) void k_statred(const float* __restrict__ pstat,
                                                 float* __restrict__ stats)
{
  __shared__ float part[16][17];
  int t = threadIdx.x;
  int j = t >> 4, s = t & 15;
  float a = 0.f;
  for (int k2 = 0; k2 < 16; ++k2) a += pstat[(size_t)(s + 16 * k2) * 16 + j];
  part[j][s] = a;
  __syncthreads();
  if (t < 16) {
    float v = 0.f;
    for (int s2 = 0; s2 < 16; ++s2) v += part[t][s2];
    stats[t] = v;
  }
}

// ---------------------- BN affine: ubb = bf16(sg*U + (bnb - sg*mc)*colsum(V))
__global__ __launch_bounds__(256) void k_bnfin(const float* __restrict__ U,
    const float* __restrict__ vcs, const float* __restrict__ stats,
    const float* __restrict__ bng, const float* __restrict__ bnb,
    u16* __restrict__ ubb)
{
  size_t idx = (size_t)blockIdx.x * 256 + threadIdx.x;
  int col = (int)(idx % 768); int i = (int)(idx / 768); int b = i >> 10;
  int g = col / 96, d = col - g * 96;
  const float cnt = 4194304.f;  // B*N*N
  float mc = stats[g] / cnt;
  float var = stats[8 + g] / cnt - mc * mc;
  float sg = bng[g] * rsqrtf(var + EPSV);
  float tg = bnb[g] - sg * mc;
  ubb[idx] = f2bf(sg * U[idx] + tg * vcs[(b * 8 + g) * 96 + d]);
}

// -------- bf16 MFMA GEMM: out = A[M,K]@W[N,K]^T + bias (+res)(+gelu)(+LN stats)
template<int GELU_, int RES_, int STATS_, int BF16OUT>
__global__ __launch_bounds__(256) void k_gemm(
    const u16* __restrict__ A, const u16* __restrict__ W,
    const float* __restrict__ bias, const float* __restrict__ res,
    float* __restrict__ out, u16* __restrict__ outb,
    int K, int Nc, float* __restrict__ stats)
{
  __shared__ u16 As[8192], Bs[8192];   // 128 rows x 64 cols, XOR-swizzled
  __shared__ float red[8];
  int t = threadIdx.x, lane = t & 63, wv = t >> 6;
  int l15 = lane & 15, lhi = lane >> 4;
  int i0 = blockIdx.y * 128, j0 = blockIdx.x * 128;
  int wr = wv >> 1, wc = wv & 1;
  f32x4 acc[4][4];
  #pragma unroll
  for (int mi = 0; mi < 4; ++mi)
    #pragma unroll
    for (int ni = 0; ni < 4; ++ni) acc[mi][ni] = (f32x4){0.f, 0.f, 0.f, 0.f};
  int rA = lane >> 3;
  int colel = 8 * ((lane & 7) ^ rA);   // pre-swizzled global source column
  for (int k0 = 0; k0 < K; k0 += 64) {
    if (k0) __syncthreads();
    #pragma unroll
    for (int i = 0; i < 4; ++i) {
      int cA = wv * 4 + i;
      int r = cA * 8 + rA;
      gload16(A + (size_t)(i0 + r) * K + k0 + colel, &As[cA * 512]);
      gload16(W + (size_t)(j0 + r) * K + k0 + colel, &Bs[cA * 512]);
    }
    __syncthreads();
    #pragma unroll
    for (int ks = 0; ks < 2; ++ks) {
      bf16x8 af[4], bf[4];
      #pragma unroll
      for (int mi = 0; mi < 4; ++mi) {
        int r2 = wr * 64 + mi * 16 + l15;
        af[mi] = *(const bf16x8*)&As[r2 * 64 + ((ks * 32 + lhi * 8) ^ (8 * (r2 & 7)))];
      }
      #pragma unroll
      for (int ni = 0; ni < 4; ++ni) {
        int r3 = wc * 64 + ni * 16 + l15;
        bf[ni] = *(const bf16x8*)&Bs[r3 * 64 + ((ks * 32 + lhi * 8) ^ (8 * (r3 & 7)))];
      }
      #pragma unroll
      for (int mi = 0; mi < 4; ++mi)
        #pragma unroll
        for (int ni = 0; ni < 4; ++ni)
          acc[mi][ni] = mfma16(af[mi], bf[ni], acc[mi][ni]);
    }
  }
  float ls = 0.f, lss = 0.f;
  #pragma unroll
  for (int mi = 0; mi < 4; ++mi) {
    #pragma unroll
    for (int ni = 0; ni < 4; ++ni) {
      int col = j0 + wc * 64 + ni * 16 + l15;
      float bv = bias[col];
      #pragma unroll
      for (int r = 0; r < 4; ++r) {
        int row = i0 + wr * 64 + mi * 16 + lhi * 4 + r;
        float val = acc[mi][ni][r] + bv;
        if (RES_) val += res[(size_t)row * Nc + col];
        if (GELU_) val = 0.5f * val * (1.f + erff(val * 0.70710678118654752f));
        if (BF16OUT) outb[(size_t)row * Nc + col] = f2bf(val);
        else out[(size_t)row * Nc + col] = val;
        if (STATS_) { ls += val; lss += val * val; }
      }
    }
  }
  if (STATS_) {
    #pragma unroll
    for (int off = 32; off > 0; off >>= 1) {
      ls += __shfl_down(ls, off); lss += __shfl_down(lss, off);
    }
    if (lane == 0) { red[wv * 2] = ls; red[wv * 2 + 1] = lss; }
    __syncthreads();
    if (t == 0) {
      int b = i0 >> 10;
      atomicAdd(&stats[b * 2],     red[0] + red[2] + red[4] + red[6]);
      atomicAdd(&stats[b * 2 + 1], red[1] + red[3] + red[5] + red[7]);
    }
  }
}

// ------------------------------- joint (N,D) LayerNorm apply (per-b scalars)
template<int BF16OUT>
__global__ __launch_bounds__(256) void k_ln(const float* __restrict__ y,
    const float* __restrict__ stats, const float* __restrict__ g,
    const float* __restrict__ bta, float* __restrict__ outp, u16* __restrict__ outb)
{
  size_t idx = (size_t)blockIdx.x * 256 + threadIdx.x;
  int i = (int)(idx / 768), col = (int)(idx % 768);
  int b = i >> 10, n = i & 1023;
  const float cnt = 786432.f;  // N*D
  float mu = stats[b * 2] / cnt;
  float var = stats[b * 2 + 1] / cnt - mu * mu;
  float r = rsqrtf(var + EPSV);
  size_t gi = (size_t)n * 768 + col;
  float v = (y[idx] - mu) * r * g[gi] + bta[gi];
  outp[idx] = v;
  if (BF16OUT) outb[idx] = f2bf(v);
}

extern "C" void kernel_launch(void* const* d_in, const int* in_sizes, int n_in,
                              void* d_out, int out_size, void* d_ws, size_t ws_size,
                              hipStream_t stream)
{
  const float* x   = (const float*)d_in[0];
  const float* qw  = (const float*)d_in[1];
  const float* kw  = (const float*)d_in[2];
  const float* vw  = (const float*)d_in[3];
  const float* rw  = (const float*)d_in[4];
  const float* bng = (const float*)d_in[6];
  const float* bnb = (const float*)d_in[7];
  const float* pw  = (const float*)d_in[8];
  const float* pb  = (const float*)d_in[9];
  const float* lng = (const float*)d_in[10];
  const float* lnb = (const float*)d_in[11];
  const float* fw1 = (const float*)d_in[12];
  const float* fb1 = (const float*)d_in[13];
  const float* fw2 = (const float*)d_in[14];
  const float* fb2 = (const float*)d_in[15];
  float* out = (float*)d_out;

  float* ws    = (float*)d_ws;
  float* stats = ws;             // 64  ([0..15] BN, [16..23] LN1, [24..31] LN2)
  float* pstat = ws + 64;        // 4096
  float* vcs   = ws + 4160;      // 3072
  float* mz    = ws + 7232;      // 65536 (M then invZ)
  float* vb    = ws + 72768;     // 3145728
  float* U     = ws + 3218496;   // 3145728
  float* x1    = ws + 6364224;   // 3145728
  u16* u16b = (u16*)(ws + 9509952);
  u16* qhi  = u16b;
  u16* qlo  = u16b + 3145728;
  u16* khi  = u16b + 6291456;
  u16* klo  = u16b + 9437184;
  u16* vtr  = u16b + 12582912;
  u16* ubb  = u16b + 15728640;
  u16* pwb  = u16b + 18874368;
  u16* fw1b = u16b + 19464192;
  u16* fw2b = u16b + 21823488;   // ends 24182784 u16 (~86 MB total ws use)
  u16* x1b = qhi;                // aliases (attention buffers dead by then)
  u16* hb  = qlo;                // spans qlo..vtr = 12582912 u16
  float* y1 = U;
  float* y2 = vb;

  hipMemsetAsync(stats, 0, 64 * sizeof(float), stream);
  k_f2b<<<1024, 256, 0, stream>>>(pw, pwb, 589824);
  k_f2b<<<2048, 256, 0, stream>>>(fw1, fw1b, 2359296);
  k_f2b<<<2048, 256, 0, stream>>>(fw2, fw2b, 2359296);

  k_conv<<<4096, 256, 0, stream>>>(x, qw, kw, vw, qhi, qlo, khi, klo, vb, vtr);
  k_passA<<<512, 256, 0, stream>>>(qhi, qlo, khi, klo, mz);
  k_vcs<<<32, 384, 0, stream>>>(vb, vcs);
  k_passB<<<256, 512, 0, stream>>>(qhi, qlo, khi, klo, vtr, mz, rw, U, pstat);
  k_statred<<<1, 256, 0, stream>>>(pstat, stats);
  k_bnfin<<<12288, 256, 0, stream>>>(U, vcs, stats, bng, bnb, ubb);

  k_gemm<0,1,1,0><<<dim3(6, 32), 256, 0, stream>>>(ubb, pwb, pb, x, y1, nullptr, 768, 768, stats + 16);
  k_ln<1><<<12288, 256, 0, stream>>>(y1, stats + 16, lng, lnb, x1, x1b);
  k_gemm<1,0,0,1><<<dim3(24, 32), 256, 0, stream>>>(x1b, fw1b, fb1, nullptr, nullptr, hb, 768, 3072, nullptr);
  k_gemm<0,1,1,0><<<dim3(6, 32), 256, 0, stream>>>(hb, fw2b, fb2, x1, y2, nullptr, 3072, 768, stats + 24);
  k_ln<0><<<12288, 256, 0, stream>>>(y2, stats + 24, lng, lnb, out, nullptr);
}

// Round 3
// 367.760 us; speedup vs baseline: 10.2816x; 1.0790x over previous
//
#include <hip/hip_runtime.h>
#include <math.h>

// ViT encoder block (DeepViT ReAttention), B=4 N=1024 D=768 H=8 hd=96 Hdim=3072
// MFMA bf16 attention (split-bf16 scores, analytic centering) + MFMA bf16 GEMMs.
// R3: passA/passB m-split (2x blocks/CU), P double-buffer (1 barrier/iter),
//     coalesced V-transpose kernel instead of conv scatter stores.

typedef unsigned short u16;
typedef unsigned int u32;
typedef __bf16 bf16x8 __attribute__((ext_vector_type(8)));
typedef float f32x4 __attribute__((ext_vector_type(4)));

#define EPSV 1e-5f
#define SCALE 0.10206207261596575f  // 96^-0.5

__device__ __forceinline__ u16 f2bf(float f) {
  union { float f; u32 u; } v; v.f = f;
  u32 u = v.u + 0x7fffu + ((v.u >> 16) & 1u);
  return (u16)(u >> 16);
}
__device__ __forceinline__ float bf2f(u16 h) {
  union { u32 u; float f; } v; v.u = ((u32)h) << 16; return v.f;
}
__device__ __forceinline__ f32x4 mfma16(bf16x8 a, bf16x8 b, f32x4 c) {
  return __builtin_amdgcn_mfma_f32_16x16x32_bf16(a, b, c, 0, 0, 0);
}
__device__ __forceinline__ void gload16(const void* gp, void* lp) {
  __builtin_amdgcn_global_load_lds(
      (const __attribute__((address_space(1))) u32*)gp,
      (__attribute__((address_space(3))) u32*)lp, 16, 0, 0);
}

// ---------------------------------------------------------------- fp32 -> bf16
__global__ __launch_bounds__(256) void k_f2b(const float* __restrict__ s,
                                             u16* __restrict__ d, int n) {
  int i = blockIdx.x * 256 + threadIdx.x;
  int stride = gridDim.x * 256;
  for (; i < n; i += stride) d[i] = f2bf(s[i]);
}

// ---------------------------------------------------------------- conv 3x3 QKV
__global__ __launch_bounds__(256) void k_conv(const float* __restrict__ x,
    const float* __restrict__ wq, const float* __restrict__ wk, const float* __restrict__ wv,
    u16* __restrict__ qhi, u16* __restrict__ qlo,
    u16* __restrict__ khi, u16* __restrict__ klo,
    float* __restrict__ vb)
{
  __shared__ float patch[768], swq[81], swk[81], swv[81];
  int bid = blockIdx.x;            // b*1024 + n
  int b = bid >> 10, n = bid & 1023;
  int t = threadIdx.x;
  const float* xr = x + (size_t)bid * 768;
  patch[t] = xr[t]; patch[t + 256] = xr[t + 256]; patch[t + 512] = xr[t + 512];
  if (t < 81) { swq[t] = wq[t]; swk[t] = wk[t]; swv[t] = wv[t]; }
  __syncthreads();
  #pragma unroll
  for (int r = 0; r < 3; ++r) {
    int f = t + 256 * r;                       // c*256 + p*16 + q
    int o = f >> 8, rem = f & 255, pp = rem >> 4, qq = rem & 15;
    float aq = 0.f, ak = 0.f, av = 0.f;
    #pragma unroll
    for (int i = 0; i < 3; ++i)
      #pragma unroll
      for (int dp = 0; dp < 3; ++dp) {
        int ip = pp + dp - 1;
        if (ip < 0 || ip > 15) continue;
        #pragma unroll
        for (int dq = 0; dq < 3; ++dq) {
          int iq = qq + dq - 1;
          if (iq < 0 || iq > 15) continue;
          float pv = patch[i * 256 + ip * 16 + iq];
          int wi = ((o * 3 + i) * 3 + dp) * 3 + dq;
          aq += swq[wi] * pv; ak += swk[wi] * pv; av += swv[wi] * pv;
        }
      }
    int h = f / 96, d = f - h * 96;
    size_t oi = ((size_t)(b * 8 + h) * 1024 + n) * 96 + d;
    u16 qh_ = f2bf(aq); qhi[oi] = qh_; qlo[oi] = f2bf(aq - bf2f(qh_));
    u16 kh_ = f2bf(ak); khi[oi] = kh_; klo[oi] = f2bf(ak - bf2f(kh_));
    vb[oi] = av;
  }
}

// ------------------------------- V transpose: [bh][n][d] f32 -> [bh][d][n] bf16
__global__ __launch_bounds__(256) void k_vtr(const float* __restrict__ vb,
                                             u16* __restrict__ vtr)
{
  __shared__ u16 lds[12288];     // [96 d][128 n]
  int bid = blockIdx.x;          // bh*8 + ntile
  int bh = bid >> 3, n0 = (bid & 7) * 128;
  int t = threadIdx.x;
  int n = t >> 1, dh = (t & 1) * 48;
  const float* src = vb + ((size_t)bh * 1024 + n0 + n) * 96 + dh;
  #pragma unroll
  for (int j4 = 0; j4 < 12; ++j4) {
    float4 v = *(const float4*)(src + j4 * 4);
    int d = dh + j4 * 4;
    lds[(d + 0) * 128 + n] = f2bf(v.x);
    lds[(d + 1) * 128 + n] = f2bf(v.y);
    lds[(d + 2) * 128 + n] = f2bf(v.z);
    lds[(d + 3) * 128 + n] = f2bf(v.w);
  }
  __syncthreads();
  #pragma unroll
  for (int j = 0; j < 48; ++j) {
    int flat = t + 256 * j;
    int d = flat >> 7, n2 = flat & 127;
    vtr[((size_t)bh * 96 + d) * 1024 + n0 + n2] = lds[flat];
  }
}

// ---------------- pass A: partial row max + exp-sum over an m-half (split-bf16)
__global__ __launch_bounds__(256) void k_passA(
    const u16* __restrict__ qhi, const u16* __restrict__ qlo,
    const u16* __restrict__ khi, const u16* __restrict__ klo,
    float* __restrict__ mzp)
{
  int bid = blockIdx.x;          // bh*32 + tile*2 + half
  int bh = bid >> 5, rest = bid & 31, tile = rest >> 1, half = rest & 1;
  int t = threadIdx.x, lane = t & 63, wv = t >> 6;
  int l15 = lane & 15, lhi = lane >> 4;
  int n0 = tile * 64 + wv * 16;
  size_t qoff = ((size_t)bh * 1024 + n0 + l15) * 96 + lhi * 8;
  bf16x8 qh[3], ql[3];
  #pragma unroll
  for (int kk = 0; kk < 3; ++kk) {
    qh[kk] = *(const bf16x8*)(qhi + qoff + kk * 32);
    ql[kk] = *(const bf16x8*)(qlo + qoff + kk * 32);
  }
  float mx[4] = {-1e30f, -1e30f, -1e30f, -1e30f};
  float zs[4] = {0.f, 0.f, 0.f, 0.f};
  int mstart = half * 512;
  for (int m0 = mstart; m0 < mstart + 512; m0 += 64) {
    f32x4 C[4];
    #pragma unroll
    for (int msub = 0; msub < 4; ++msub) {
      size_t koff = ((size_t)bh * 1024 + m0 + msub * 16 + l15) * 96 + lhi * 8;
      f32x4 Cc = {0.f, 0.f, 0.f, 0.f};
      #pragma unroll
      for (int kk = 0; kk < 3; ++kk) {
        bf16x8 kh = *(const bf16x8*)(khi + koff + kk * 32);
        bf16x8 kl = *(const bf16x8*)(klo + koff + kk * 32);
        Cc = mfma16(qh[kk], kh, Cc);
        Cc = mfma16(qh[kk], kl, Cc);
        Cc = mfma16(ql[kk], kh, Cc);
      }
      C[msub] = Cc;
    }
    #pragma unroll
    for (int r = 0; r < 4; ++r) {
      float v0 = C[0][r] * SCALE, v1 = C[1][r] * SCALE;
      float v2 = C[2][r] * SCALE, v3 = C[3][r] * SCALE;
      float cm = fmaxf(fmaxf(v0, v1), fmaxf(v2, v3));
      float nm = fmaxf(mx[r], cm);
      zs[r] = zs[r] * __expf(mx[r] - nm) +
              __expf(v0 - nm) + __expf(v1 - nm) + __expf(v2 - nm) + __expf(v3 - nm);
      mx[r] = nm;
    }
  }
  #pragma unroll
  for (int off = 1; off < 16; off <<= 1) {
    #pragma unroll
    for (int r = 0; r < 4; ++r) {
      float om = __shfl_xor(mx[r], off);
      float oz = __shfl_xor(zs[r], off);
      float nm = fmaxf(mx[r], om);
      zs[r] = zs[r] * __expf(mx[r] - nm) + oz * __expf(om - nm);
      mx[r] = nm;
    }
  }
  if (l15 == 0) {
    #pragma unroll
    for (int r = 0; r < 4; ++r) {
      int idx = bh * 1024 + n0 + lhi * 4 + r;
      mzp[half * 65536 + idx] = mx[r];
      mzp[half * 65536 + 32768 + idx] = zs[r];
    }
  }
}

// --------------------------------------- merge the two m-half (M, Z) partials
__global__ __launch_bounds__(256) void k_mzmerge(const float* __restrict__ mzp,
                                                 float* __restrict__ mz)
{
  int idx = blockIdx.x * 256 + threadIdx.x;   // < 32768
  float m0 = mzp[idx],         z0 = mzp[32768 + idx];
  float m1 = mzp[65536 + idx], z1 = mzp[98304 + idx];
  float M = fmaxf(m0, m1);
  float Z = z0 * __expf(m0 - M) + z1 * __expf(m1 - M);
  mz[idx] = M;
  mz[32768 + idx] = 1.f / Z;
}

// ---------------- pass B: P (softmax) -> centered head-mix -> BN stats + U=c@V
// grid 512: (b, ntile, mhalf); partial U per half, summed in k_bnfin.
__global__ __launch_bounds__(512) void k_passB(
    const u16* __restrict__ qhi, const u16* __restrict__ qlo,
    const u16* __restrict__ khi, const u16* __restrict__ klo,
    const u16* __restrict__ vtr, const float* __restrict__ mz,
    const float* __restrict__ rw, float* __restrict__ U, float* __restrict__ pstat)
{
  __shared__ float P[2][4096];        // dbuf: [h][n(16)][m(32)] swizzled
  __shared__ float Msm[128], Zsm[128];
  int bid = blockIdx.x;
  int b = bid >> 7, rest = bid & 127, tile = rest >> 1, half = rest & 1;
  int n0 = tile * 16;
  int t = threadIdx.x, lane = t & 63, wv = t >> 6;  // wv = head
  int l15 = lane & 15, lhi = lane >> 4;
  if (t < 128) {
    int h = t >> 4, rr = t & 15;
    int idx = (b * 8 + h) * 1024 + n0 + rr;
    Msm[t] = mz[idx];
    Zsm[t] = mz[32768 + idx];
  }
  float wg[8]; float wsum = 0.f;
  #pragma unroll
  for (int h = 0; h < 8; ++h) { wg[h] = rw[wv * 8 + h]; wsum += wg[h]; }
  float cg = -wsum * (1.f / 1024.f);   // analytic centering (reatten_b cancels)
  size_t qoff = ((size_t)(b * 8 + wv) * 1024 + n0 + l15) * 96 + lhi * 8;
  bf16x8 qh[3], ql[3];
  #pragma unroll
  for (int kk = 0; kk < 3; ++kk) {
    qh[kk] = *(const bf16x8*)(qhi + qoff + kk * 32);
    ql[kk] = *(const bf16x8*)(qlo + qoff + kk * 32);
  }
  f32x4 acc[6];
  #pragma unroll
  for (int ds = 0; ds < 6; ++ds) acc[ds] = (f32x4){0.f, 0.f, 0.f, 0.f};
  float sc = 0.f, scc = 0.f;
  __syncthreads();
  for (int it = 0; it < 16; ++it) {
    int m0 = half * 512 + it * 32;
    float* Pb = &P[it & 1][0];
    #pragma unroll
    for (int msub = 0; msub < 2; ++msub) {
      size_t koff = ((size_t)(b * 8 + wv) * 1024 + m0 + msub * 16 + l15) * 96 + lhi * 8;
      f32x4 C = {0.f, 0.f, 0.f, 0.f};
      #pragma unroll
      for (int kk = 0; kk < 3; ++kk) {
        bf16x8 kh = *(const bf16x8*)(khi + koff + kk * 32);
        bf16x8 kl = *(const bf16x8*)(klo + koff + kk * 32);
        C = mfma16(qh[kk], kh, C);
        C = mfma16(qh[kk], kl, C);
        C = mfma16(ql[kk], kh, C);
      }
      #pragma unroll
      for (int r = 0; r < 4; ++r) {
        int n = lhi * 4 + r;
        float p = __expf(C[r] * SCALE - Msm[wv * 16 + n]) * Zsm[wv * 16 + n];
        int m = msub * 16 + l15;
        Pb[wv * 512 + n * 32 + (m ^ (4 * (n & 7)))] = p;
      }
    }
    __syncthreads();
    {
      int n = l15, mask = 4 * (n & 7);
      int m0r = lhi * 8;
      float c8[8];
      #pragma unroll
      for (int j = 0; j < 8; ++j) c8[j] = cg;
      #pragma unroll
      for (int h = 0; h < 8; ++h) {
        const float* Ph = &Pb[h * 512 + n * 32];
        float4 p0 = *(const float4*)&Ph[(m0r) ^ mask];
        float4 p1 = *(const float4*)&Ph[(m0r + 4) ^ mask];
        c8[0] += wg[h] * p0.x; c8[1] += wg[h] * p0.y;
        c8[2] += wg[h] * p0.z; c8[3] += wg[h] * p0.w;
        c8[4] += wg[h] * p1.x; c8[5] += wg[h] * p1.y;
        c8[6] += wg[h] * p1.z; c8[7] += wg[h] * p1.w;
      }
      union { u16 us[8]; bf16x8 bv; } pk;
      #pragma unroll
      for (int j = 0; j < 8; ++j) {
        sc += c8[j]; scc += c8[j] * c8[j];
        pk.us[j] = f2bf(c8[j]);
      }
      #pragma unroll
      for (int ds = 0; ds < 6; ++ds) {
        size_t voff = ((size_t)(b * 8 + wv) * 96 + ds * 16 + l15) * 1024 + m0 + lhi * 8;
        bf16x8 bv = *(const bf16x8*)(vtr + voff);
        acc[ds] = mfma16(pk.bv, bv, acc[ds]);
      }
    }
  }
  #pragma unroll
  for (int ds = 0; ds < 6; ++ds)
    #pragma unroll
    for (int r = 0; r < 4; ++r) {
      int n = lhi * 4 + r;
      U[(size_t)half * 3145728 +
        ((size_t)(b * 1024 + n0 + n)) * 768 + wv * 96 + ds * 16 + l15] = acc[ds][r];
    }
  #pragma unroll
  for (int off = 32; off > 0; off >>= 1) {
    sc += __shfl_down(sc, off); scc += __shfl_down(scc, off);
  }
  if (lane == 0) { pstat[bid * 16 + wv] = sc; pstat[bid * 16 + 8 + wv] = scc; }
}

// ------------------------------------------------- colsum(V) per (b,h,d), fp32
__global__ __launch_bounds__(384) void k_vcs(const float* __restrict__ vb,
                                             float* __restrict__ vcs)
{
  __shared__ float part[4][96];
  int bh = blockIdx.x, t = threadIdx.x;
  int c = t % 96, g4 = t / 96;
  float a = 0.f;
  const float* vp = vb + (size_t)bh * 98304 + (size_t)g4 * 24576 + c;
  for (int m = 0; m < 256; ++m) a += vp[m * 96];
  part[g4][c] = a;
  __syncthreads();
  if (t < 96) vcs[bh * 96 + t] = part[0][t] + part[1][t] + part[2][t] + part[3][t];
}

// ------------------------------------------------- BN partial reduce (512x16)
__global__ __launch_bounds__(256) void k_statred(const float* __restrict__ pstat,
                                                 float* __restrict__ stats)
{
  __shared__ float part[16][17];
  int t = threadIdx.x;
  int j = t >> 4, s = t & 15;
  float a = 0.f;
  for (int k2 = 0; k2 < 32; ++k2) a += pstat[(size_t)(s + 16 * k2) * 16 + j];
  part[j][s] = a;
  __syncthreads();
  if (t < 16) {
    float v = 0.f;
    for (int s2 = 0; s2 < 16; ++s2) v += part[t][s2];
    stats[t] = v;
  }
}

// ------------- BN affine: ubb = bf16(sg*(U0+U1) + (bnb - sg*mc)*colsum(V))
__global__ __launch_bounds__(256) void k_bnfin(const float* __restrict__ U,
    const float* __restrict__ vcs, const float* __restrict__ stats,
    const float* __restrict__ bng, const float* __restrict__ bnb,
    u16* __restrict__ ubb)
{
  size_t idx = (size_t)blockIdx.x * 256 + threadIdx.x;
  int col = (int)(idx % 768); int i = (int)(idx / 768); int b = i >> 10;
  int g = col / 96, d = col - g * 96;
  const float cnt = 4194304.f;  // B*N*N
  float mc = stats[g] / cnt;
  float var = stats[8 + g] / cnt - mc * mc;
  float sg = bng[g] * rsqrtf(var + EPSV);
  float tg = bnb[g] - sg * mc;
  float u = U[idx] + U[idx + 3145728];
  ubb[idx] = f2bf(sg * u + tg * vcs[(b * 8 + g) * 96 + d]);
}

// -------- bf16 MFMA GEMM: out = A[M,K]@W[N,K]^T + bias (+res)(+gelu)(+LN stats)
template<int GELU_, int RES_, int STATS_, int BF16OUT>
__global__ __launch_bounds__(256) void k_gemm(
    const u16* __restrict__ A, const u16* __restrict__ W,
    const float* __restrict__ bias, const float* __restrict__ res,
    float* __restrict__ out, u16* __restrict__ outb,
    int K, int Nc, float* __restrict__ stats)
{
  __shared__ u16 As[8192], Bs[8192];   // 128 rows x 64 cols, XOR-swizzled
  __shared__ float red[8];
  int t = threadIdx.x, lane = t & 63, wv = t >> 6;
  int l15 = lane & 15, lhi = lane >> 4;
  int i0 = blockIdx.y * 128, j0 = blockIdx.x * 128;
  int wr = wv >> 1, wc = wv & 1;
  f32x4 acc[4][4];
  #pragma unroll
  for (int mi = 0; mi < 4; ++mi)
    #pragma unroll
    for (int ni = 0; ni < 4; ++ni) acc[mi][ni] = (f32x4){0.f, 0.f, 0.f, 0.f};
  int rA = lane >> 3;
  int colel = 8 * ((lane & 7) ^ rA);   // pre-swizzled global source column
  for (int k0 = 0; k0 < K; k0 += 64) {
    if (k0) __syncthreads();
    #pragma unroll
    for (int i = 0; i < 4; ++i) {
      int cA = wv * 4 + i;
      int r = cA * 8 + rA;
      gload16(A + (size_t)(i0 + r) * K + k0 + colel, &As[cA * 512]);
      gload16(W + (size_t)(j0 + r) * K + k0 + colel, &Bs[cA * 512]);
    }
    __syncthreads();
    #pragma unroll
    for (int ks = 0; ks < 2; ++ks) {
      bf16x8 af[4], bf[4];
      #pragma unroll
      for (int mi = 0; mi < 4; ++mi) {
        int r2 = wr * 64 + mi * 16 + l15;
        af[mi] = *(const bf16x8*)&As[r2 * 64 + ((ks * 32 + lhi * 8) ^ (8 * (r2 & 7)))];
      }
      #pragma unroll
      for (int ni = 0; ni < 4; ++ni) {
        int r3 = wc * 64 + ni * 16 + l15;
        bf[ni] = *(const bf16x8*)&Bs[r3 * 64 + ((ks * 32 + lhi * 8) ^ (8 * (r3 & 7)))];
      }
      #pragma unroll
      for (int mi = 0; mi < 4; ++mi)
        #pragma unroll
        for (int ni = 0; ni < 4; ++ni)
          acc[mi][ni] = mfma16(af[mi], bf[ni], acc[mi][ni]);
    }
  }
  float ls = 0.f, lss = 0.f;
  #pragma unroll
  for (int mi = 0; mi < 4; ++mi) {
    #pragma unroll
    for (int ni = 0; ni < 4; ++ni) {
      int col = j0 + wc * 64 + ni * 16 + l15;
      float bv = bias[col];
      #pragma unroll
      for (int r = 0; r < 4; ++r) {
        int row = i0 + wr * 64 + mi * 16 + lhi * 4 + r;
        float val = acc[mi][ni][r] + bv;
        if (RES_) val += res[(size_t)row * Nc + col];
        if (GELU_) val = 0.5f * val * (1.f + erff(val * 0.70710678118654752f));
        if (BF16OUT) outb[(size_t)row * Nc + col] = f2bf(val);
        else out[(size_t)row * Nc + col] = val;
        if (STATS_) { ls += val; lss += val * val; }
      }
    }
  }
  if (STATS_) {
    #pragma unroll
    for (int off = 32; off > 0; off >>= 1) {
      ls += __shfl_down(ls, off); lss += __shfl_down(lss, off);
    }
    if (lane == 0) { red[wv * 2] = ls; red[wv * 2 + 1] = lss; }
    __syncthreads();
    if (t == 0) {
      int b = i0 >> 10;
      atomicAdd(&stats[b * 2],     red[0] + red[2] + red[4] + red[6]);
      atomicAdd(&stats[b * 2 + 1], red[1] + red[3] + red[5] + red[7]);
    }
  }
}

// ------------------------------- joint (N,D) LayerNorm apply (per-b scalars)
template<int BF16OUT>
__global__ __launch_bounds__(256) void k_ln(const float* __restrict__ y,
    const float* __restrict__ stats, const float* __restrict__ g,
    const float* __restrict__ bta, float* __restrict__ outp, u16* __restrict__ outb)
{
  size_t idx = (size_t)blockIdx.x * 256 + threadIdx.x;
  int i = (int)(idx / 768), col = (int)(idx % 768);
  int b = i >> 10, n = i & 1023;
  const float cnt = 786432.f;  // N*D
  float mu = stats[b * 2] / cnt;
  float var = stats[b * 2 + 1] / cnt - mu * mu;
  float r = rsqrtf(var + EPSV);
  size_t gi = (size_t)n * 768 + col;
  float v = (y[idx] - mu) * r * g[gi] + bta[gi];
  outp[idx] = v;
  if (BF16OUT) outb[idx] = f2bf(v);
}

extern "C" void kernel_launch(void* const* d_in, const int* in_sizes, int n_in,
                              void* d_out, int out_size, void* d_ws, size_t ws_size,
                              hipStream_t stream)
{
  const float* x   = (const float*)d_in[0];
  const float* qw  = (const float*)d_in[1];
  const float* kw  = (const float*)d_in[2];
  const float* vw  = (const float*)d_in[3];
  const float* rw  = (const float*)d_in[4];
  const float* bng = (const float*)d_in[6];
  const float* bnb = (const float*)d_in[7];
  const float* pw  = (const float*)d_in[8];
  const float* pb  = (const float*)d_in[9];
  const float* lng = (const float*)d_in[10];
  const float* lnb = (const float*)d_in[11];
  const float* fw1 = (const float*)d_in[12];
  const float* fb1 = (const float*)d_in[13];
  const float* fw2 = (const float*)d_in[14];
  const float* fb2 = (const float*)d_in[15];
  float* out = (float*)d_out;

  float* ws    = (float*)d_ws;
  float* stats = ws;                  // 64  ([0..15] BN, [16..23] LN1, [24..31] LN2)
  float* pstat = ws + 64;             // 8192 (512 blocks x 16)
  float* vcs   = ws + 8256;           // 3072
  float* mzp   = ws + 11328;          // 131072 (2 halves x (M,Z))
  float* mz    = ws + 142400;         // 65536 (M then invZ)
  float* vb    = ws + 207936;         // 3145728
  float* U     = ws + 3353664;        // 2 x 3145728 (m-half partials)
  float* x1    = ws + 9645120;        // 3145728
  u16* u16b = (u16*)(ws + 12790848);
  u16* qhi  = u16b;
  u16* qlo  = u16b + 3145728;
  u16* khi  = u16b + 6291456;
  u16* klo  = u16b + 9437184;
  u16* vtr  = u16b + 12582912;
  u16* ubb  = u16b + 15728640;
  u16* pwb  = u16b + 18874368;
  u16* fw1b = u16b + 19464192;
  u16* fw2b = u16b + 21823488;        // ends 24182784 u16 (~100 MB total ws use)
  u16* x1b = qhi;                     // aliases (attention buffers dead by then)
  u16* hb  = qlo;                     // spans qlo..vtr = 12582912 u16
  float* y1 = U;
  float* y2 = vb;

  hipMemsetAsync(stats, 0, 64 * sizeof(float), stream);
  k_f2b<<<1024, 256, 0, stream>>>(pw, pwb, 589824);
  k_f2b<<<2048, 256, 0, stream>>>(fw1, fw1b, 2359296);
  k_f2b<<<2048, 256, 0, stream>>>(fw2, fw2b, 2359296);

  k_conv<<<4096, 256, 0, stream>>>(x, qw, kw, vw, qhi, qlo, khi, klo, vb);
  k_passA<<<1024, 256, 0, stream>>>(qhi, qlo, khi, klo, mzp);
  k_vtr<<<256, 256, 0, stream>>>(vb, vtr);
  k_vcs<<<32, 384, 0, stream>>>(vb, vcs);
  k_mzmerge<<<128, 256, 0, stream>>>(mzp, mz);
  k_passB<<<512, 512, 0, stream>>>(qhi, qlo, khi, klo, vtr, mz, rw, U, pstat);
  k_statred<<<1, 256, 0, stream>>>(pstat, stats);
  k_bnfin<<<12288, 256, 0, stream>>>(U, vcs, stats, bng, bnb, ubb);

  k_gemm<0,1,1,0><<<dim3(6, 32), 256, 0, stream>>>(ubb, pwb, pb, x, y1, nullptr, 768, 768, stats + 16);
  k_ln<1><<<12288, 256, 0, stream>>>(y1, stats + 16, lng, lnb, x1, x1b);
  k_gemm<1,0,0,1><<<dim3(24, 32), 256, 0, stream>>>(x1b, fw1b, fb1, nullptr, nullptr, hb, 768, 3072, nullptr);
  k_gemm<0,1,1,0><<<dim3(6, 32), 256, 0, stream>>>(hb, fw2b, fb2, x1, y2, nullptr, 3072, 768, stats + 24);
  k_ln<0><<<12288, 256, 0, stream>>>(y2, stats + 24, lng, lnb, out, nullptr);
}